// Round 1
// baseline (1532.434 us; speedup 1.0000x reference)
//
#include <hip/hip_runtime.h>
#include <hip/hip_bf16.h>
#include <math.h>

#define B_   16
#define CIN  64
#define COUT 64
#define H_   256
#define W_   256

// conv tiling
#define WT   64   // output cols per block (== lanes)
#define HT   8    // output rows per block
#define OCT  16   // output channels per block
#define ICT  8    // input-channel chunk staged in LDS

// ---------------------------------------------------------------------------
// 1) pooled[b*64+c] = mean over H*W of inputs[b][c][:][:]
__global__ __launch_bounds__(256) void pool_kernel(const float* __restrict__ x,
                                                   float* __restrict__ pooled) {
    const int plane = blockIdx.x;  // 0..1023 = b*64+c
    const float4* p = (const float4*)(x + (size_t)plane * (H_ * W_));
    float s = 0.f;
    for (int i = threadIdx.x; i < (H_ * W_) / 4; i += 256) {
        float4 v = p[i];
        s += (v.x + v.y) + (v.z + v.w);
    }
    #pragma unroll
    for (int off = 32; off > 0; off >>= 1) s += __shfl_down(s, off);
    __shared__ float red[4];
    if ((threadIdx.x & 63) == 0) red[threadIdx.x >> 6] = s;
    __syncthreads();
    if (threadIdx.x == 0)
        pooled[plane] = (red[0] + red[1] + red[2] + red[3]) * (1.f / (H_ * W_));
}

// ---------------------------------------------------------------------------
// 2) routing[b*4+e] = sigmoid(dot(pooled[b], fc_w[e]) + fc_b[e])
__global__ void routing_kernel(const float* __restrict__ pooled,
                               const float* __restrict__ fc_w,
                               const float* __restrict__ fc_b,
                               float* __restrict__ routing) {
    const int tid = threadIdx.x;          // 64 threads
    const int b = tid >> 2, e = tid & 3;
    float s = fc_b[e];
    for (int c = 0; c < CIN; ++c) s += pooled[b * CIN + c] * fc_w[e * CIN + c];
    routing[b * 4 + e] = 1.f / (1.f + expf(-s));
}

// ---------------------------------------------------------------------------
// 3) mixed[b][oc][ic][tap] = sum_e routing[b][e] * weight[e][oc][ic][tap]
__global__ __launch_bounds__(256) void mix_kernel(const float* __restrict__ routing,
                                                  const float* __restrict__ weight,
                                                  float* __restrict__ mixed) {
    const int idx = blockIdx.x * 256 + threadIdx.x;  // 0..589823
    const int per = COUT * CIN * 9;                  // 36864
    const int b = idx / per;
    const int r = idx - b * per;
    float s = 0.f;
    #pragma unroll
    for (int e = 0; e < 4; ++e)
        s += routing[b * 4 + e] * weight[(size_t)e * per + r];
    mixed[idx] = s;
}

// ---------------------------------------------------------------------------
// 4) conv: y[b][oc][h][w] = sum_{ic,kh,kw} x[b][ic][h+kh-1][w+kw-1]*mixed[b][oc][ic][kh*3+kw]
// grid: (4 w-tiles, 32 h-tiles, B*4 oc-groups). block 256 = 4 waves.
// lane = w within tile; tid>>6 selects 4-oc subgroup.
__global__ __launch_bounds__(256) void conv_kernel(const float* __restrict__ x,
                                                   const float* __restrict__ wk,
                                                   float* __restrict__ y) {
    const int w0  = blockIdx.x * WT;
    const int h0  = blockIdx.y * HT;
    const int b   = blockIdx.z >> 2;
    const int oc0 = (blockIdx.z & 3) * OCT;

    __shared__ float in_s[ICT][HT + 2][WT + 2];   // 8*10*66 floats = 21.1 KB
    __shared__ float wt_s[ICT][OCT][9];           // 4.6 KB, [ic][oc][tap]

    const int tid  = threadIdx.x;
    const int lane = tid & 63;
    const int toc  = tid >> 6;                    // 0..3: my ocs = oc0+toc*4 .. +3

    float acc[HT][4];
    #pragma unroll
    for (int hh = 0; hh < HT; ++hh)
        #pragma unroll
        for (int o = 0; o < 4; ++o) acc[hh][o] = 0.f;

    const float* xb = x + (size_t)b * CIN * H_ * W_;
    const float* wb = wk + ((size_t)b * COUT + oc0) * CIN * 9;

    #pragma unroll 1
    for (int ic0 = 0; ic0 < CIN; ic0 += ICT) {
        __syncthreads();
        // stage input tile (with zero halo for padding)
        for (int idx = tid; idx < ICT * (HT + 2) * (WT + 2); idx += 256) {
            const int ic  = idx / ((HT + 2) * (WT + 2));
            const int rem = idx - ic * ((HT + 2) * (WT + 2));
            const int r   = rem / (WT + 2);
            const int c   = rem - r * (WT + 2);
            const int gh = h0 - 1 + r;
            const int gw = w0 - 1 + c;
            float v = 0.f;
            if ((unsigned)gh < H_ && (unsigned)gw < W_)
                v = xb[(size_t)(ic0 + ic) * H_ * W_ + gh * W_ + gw];
            in_s[ic][r][c] = v;
        }
        // stage weights: wt_s[ic][oc][tap]
        for (int idx = tid; idx < ICT * OCT * 9; idx += 256) {
            const int ic  = idx / (OCT * 9);
            const int rem = idx - ic * (OCT * 9);
            const int oc  = rem / 9;
            const int tap = rem - oc * 9;
            wt_s[ic][oc][tap] = wb[((size_t)oc * CIN + ic0 + ic) * 9 + tap];
        }
        __syncthreads();

        #pragma unroll 1
        for (int ic = 0; ic < ICT; ++ic) {
            // my 4 ocs' weights for this ic -> registers (36 contiguous floats)
            float wreg[4][9];
            #pragma unroll
            for (int o = 0; o < 4; ++o)
                #pragma unroll
                for (int t = 0; t < 9; ++t)
                    wreg[o][t] = wt_s[ic][toc * 4 + o][t];

            // sliding 3-row window along h
            float win0[3], win1[3];
            #pragma unroll
            for (int c = 0; c < 3; ++c) {
                win0[c] = in_s[ic][0][lane + c];
                win1[c] = in_s[ic][1][lane + c];
            }
            #pragma unroll
            for (int hh = 0; hh < HT; ++hh) {
                float win2[3];
                #pragma unroll
                for (int c = 0; c < 3; ++c) win2[c] = in_s[ic][hh + 2][lane + c];
                #pragma unroll
                for (int o = 0; o < 4; ++o) {
                    float s = acc[hh][o];
                    s = fmaf(win0[0], wreg[o][0], s);
                    s = fmaf(win0[1], wreg[o][1], s);
                    s = fmaf(win0[2], wreg[o][2], s);
                    s = fmaf(win1[0], wreg[o][3], s);
                    s = fmaf(win1[1], wreg[o][4], s);
                    s = fmaf(win1[2], wreg[o][5], s);
                    s = fmaf(win2[0], wreg[o][6], s);
                    s = fmaf(win2[1], wreg[o][7], s);
                    s = fmaf(win2[2], wreg[o][8], s);
                    acc[hh][o] = s;
                }
                #pragma unroll
                for (int c = 0; c < 3; ++c) { win0[c] = win1[c]; win1[c] = win2[c]; }
            }
        }
    }

    // epilogue: coalesced stores (lane == w)
    #pragma unroll
    for (int hh = 0; hh < HT; ++hh)
        #pragma unroll
        for (int o = 0; o < 4; ++o) {
            const int oc = oc0 + toc * 4 + o;
            y[(((size_t)b * COUT + oc) * H_ + (h0 + hh)) * W_ + w0 + lane] = acc[hh][o];
        }
}

// ---------------------------------------------------------------------------
extern "C" void kernel_launch(void* const* d_in, const int* in_sizes, int n_in,
                              void* d_out, int out_size, void* d_ws, size_t ws_size,
                              hipStream_t stream) {
    const float* x      = (const float*)d_in[0];  // [16,64,256,256]
    const float* weight = (const float*)d_in[1];  // [4,64,64,3,3]
    const float* fc_w   = (const float*)d_in[2];  // [4,64]
    const float* fc_b   = (const float*)d_in[3];  // [4]
    // stride/dilation/padding are fixed at 1/1/1 per setup_inputs.
    float* out = (float*)d_out;

    float* ws      = (float*)d_ws;
    float* pooled  = ws;          // 1024 floats
    float* routing = ws + 1024;   // 64 floats
    float* mixed   = ws + 1088;   // 589824 floats  (total ~2.36 MB)

    pool_kernel<<<B_ * CIN, 256, 0, stream>>>(x, pooled);
    routing_kernel<<<1, 64, 0, stream>>>(pooled, fc_w, fc_b, routing);
    mix_kernel<<<(B_ * COUT * CIN * 9) / 256, 256, 0, stream>>>(routing, weight, mixed);

    dim3 grid(W_ / WT, H_ / HT, B_ * (COUT / OCT));
    conv_kernel<<<grid, 256, 0, stream>>>(x, mixed, out);
}